// Round 4
// baseline (156.316 us; speedup 1.0000x reference)
//
#include <hip/hip_runtime.h>
#include <hip/hip_bf16.h>

#define B_ 16
#define S_ 512
#define H_ 768
#define TS_ 20
#define IS_ 20
#define D_ 808
#define M_ 36
#define E_ 12
#define RNUM_ 97
#define D2_ 50
#define P_ (E_*E_)        // 144
#define NODES_ (M_+1)     // 37
#define NCOL_ (D2_*D_)    // 40400
#define MROWS_ (B_*E_)    // 192
#define KSTEPS_ 26
#define KPAD_ (KSTEPS_*32)  // 832

typedef __attribute__((ext_vector_type(8))) short bf16x8;
typedef __attribute__((ext_vector_type(4))) float f32x4;

__device__ inline unsigned short f2bf(float f) {
  union { float f; unsigned u; } v; v.f = f;
  unsigned r = v.u + 0x7FFFu + ((v.u >> 16) & 1u);
  return (unsigned short)(r >> 16);
}

__device__ inline unsigned pack2bf(float a, float b) {
  union { __hip_bfloat162 h; unsigned u; } p;
  p.h = __float22bfloat162_rn(make_float2(a, b));
  return p.u;
}

// ---------------- kernel 1: mention mean-pooling (+ cls node) ----------------
__global__ __launch_bounds__(256) void k_mention_pool(
    const float* __restrict__ enc_hid, const int* __restrict__ etype,
    const int* __restrict__ eidv, const int* __restrict__ midv,
    const float* __restrict__ type_emb, const float* __restrict__ id_emb,
    float* __restrict__ x) {
  int blk = blockIdx.x;
  int b = blk / NODES_;
  int n = blk % NODES_;
  int t = threadIdx.x;
  float* xrow = x + (size_t)(b * NODES_ + n) * D_;
  if (n == 0) {
    for (int d = t; d < D_; d += 256)
      xrow[d] = (d < H_) ? enc_hid[(size_t)(b * S_) * H_ + d] : 0.0f;
    return;
  }
  float acc[4] = {0.f, 0.f, 0.f, 0.f};
  int cnt = 0;
  for (int s = 0; s < S_; ++s) {
    int m = midv[b * S_ + s];
    if (m != n) continue;
    ++cnt;
    int ty = etype[b * S_ + s];
    int iv = eidv[b * S_ + s];
    #pragma unroll
    for (int ii = 0; ii < 4; ++ii) {
      int d = t + ii * 256;
      if (d < D_) {
        float v;
        if (d < H_) v = enc_hid[(size_t)(b * S_ + s) * H_ + d];
        else if (d < H_ + TS_) v = type_emb[ty * TS_ + (d - H_)];
        else v = id_emb[iv * IS_ + (d - H_ - TS_)];
        acc[ii] += v;
      }
    }
  }
  float inv = (cnt > 0) ? 1.0f / (float)cnt : 0.0f;
  #pragma unroll
  for (int ii = 0; ii < 4; ++ii) {
    int d = t + ii * 256;
    if (d < D_) xrow[d] = acc[ii] * inv;
  }
}

// ---------------- kernel 2: entity pooling + bf16 pre-swizzled A -------------
// ent fp32 [192][808]; eswz bf16 layout [kb=26][g=4][row=192][8] zero-padded.
__global__ __launch_bounds__(256) void k_entity_pool(
    const float* __restrict__ x, const float* __restrict__ tbl,
    float* __restrict__ ent, short* __restrict__ eswz) {
  int blk = blockIdx.x;
  int b = blk / E_;
  int e = blk % E_;
  int t = threadIdx.x;
  const float* trow = tbl + (size_t)(b * (E_ + 1) + (e + 1)) * NODES_;
  __shared__ float w[NODES_];
  __shared__ float sinv;
  if (t < NODES_) w[t] = trow[t];
  __syncthreads();
  if (t == 0) {
    float s = 0.f;
    for (int m = 0; m < NODES_; ++m) s += w[m];
    sinv = (s > 0.f) ? 1.0f / s : 0.0f;
  }
  __syncthreads();
  float inv = sinv;
  for (int d = t; d < D_; d += 256) {
    float a = 0.f;
    for (int m = 0; m < NODES_; ++m)
      a += w[m] * x[(size_t)(b * NODES_ + m) * D_ + d];
    float v = a * inv;
    ent[(size_t)blk * D_ + d] = v;
    int kb = d >> 5, g = (d >> 3) & 3, el = d & 7;
    eswz[((size_t)(kb * 4 + g) * MROWS_ + blk) * 8 + el] = (short)f2bf(v);
  }
  if (t < KPAD_ - D_) {   // zero-pad k = 808..831
    int d = D_ + t;
    int kb = d >> 5, g = (d >> 3) & 3, el = d & 7;
    eswz[((size_t)(kb * 4 + g) * MROWS_ + blk) * 8 + el] = 0;
  }
}

// ---------------- kernel 3: A[192,40400] = Ent @ Wview -----------------------
// BM=192 BN=64 BK=32. Reg-staged W: fp32 global (coalesced) -> cvt bf16 ->
// XOR-swizzled col-major LDS [col][32k] (64B/col). B-frags = ds_read_b128.
// A-frags = direct bf16 global from pre-swizzled eswz (L2-hot).
// 2-buf LDS, loads issued 2 tiles ahead, cvt/write 1 tile ahead.
__global__ __launch_bounds__(256) void k_gemm(
    const float* __restrict__ Wf, const short* __restrict__ eswz,
    float* __restrict__ A) {
  __shared__ short Bs[2][2048];     // 2 x 4096 B
  const int tid = threadIdx.x;
  const int lane = tid & 63;
  const int ln15 = lane & 15;
  const int g = lane >> 4;
  const int wv = tid >> 6;
  const int colBase = blockIdx.x * 64;

  // staging: thread owns column scol, k-quads {skq, skq+4}
  const int scol = tid & 63;
  const int skq = tid >> 6;          // 0..3
  const int colG = colBase + scol;
  const bool cok = colG < NCOL_;
  const size_t wcol = (size_t)(cok ? colG : 0);

  f32x4 acc[3][4];
  #pragma unroll
  for (int i = 0; i < 3; ++i)
    #pragma unroll
    for (int j = 0; j < 4; ++j)
      acc[i][j] = (f32x4){0.f, 0.f, 0.f, 0.f};

  float v[8];
  // LOAD(t): 8 coalesced scalar loads of W into regs
  auto LOAD = [&](int t) {
    #pragma unroll
    for (int r = 0; r < 2; ++r)
      #pragma unroll
      for (int e = 0; e < 4; ++e) {
        int k = t * 32 + (skq + 4 * r) * 4 + e;
        v[r * 4 + e] = (cok && k < D_) ? Wf[(size_t)k * NCOL_ + wcol] : 0.0f;
      }
  };
  // WRITE(buf): cvt regs -> bf16, 2x ds_write_b64 into swizzled layout
  auto WRITE = [&](int buf) {
    #pragma unroll
    for (int r = 0; r < 2; ++r) {
      uint2 wq;
      wq.x = pack2bf(v[r * 4 + 0], v[r * 4 + 1]);
      wq.y = pack2bf(v[r * 4 + 2], v[r * 4 + 3]);
      int kq = skq + 4 * r;
      int byte = (scol * 64 + kq * 8) ^ ((scol & 7) << 4);
      *(uint2*)((char*)&Bs[buf][0] + byte) = wq;
    }
  };

  // prologue: tile0 -> buf0; issue loads for tile1
  LOAD(0);
  WRITE(0);
  LOAD(1);
  __syncthreads();

  for (int t = 0; t < KSTEPS_; ++t) {
    const int buf = t & 1;
    // cvt+write tile t+1 into other buffer (auto-waits its loads)
    if (t + 1 < KSTEPS_) WRITE(buf ^ 1);
    // issue loads for tile t+2
    if (t + 2 < KSTEPS_) LOAD(t + 2);
    // A fragments: direct global bf16 (pre-swizzled, L2-resident)
    bf16x8 af[3];
    const short* ab = eswz + ((size_t)(t * 4 + g) * MROWS_ + wv * 48 + ln15) * 8;
    af[0] = *(const bf16x8*)(ab);
    af[1] = *(const bf16x8*)(ab + 16 * 8);
    af[2] = *(const bf16x8*)(ab + 32 * 8);
    // B fragments: swizzled ds_read_b128
    bf16x8 bfr[4];
    #pragma unroll
    for (int nt = 0; nt < 4; ++nt) {
      int col = nt * 16 + ln15;
      int byte = (col * 64 + g * 16) ^ ((col & 7) << 4);
      bfr[nt] = *(const bf16x8*)((const char*)&Bs[buf][0] + byte);
    }
    #pragma unroll
    for (int mt = 0; mt < 3; ++mt)
      #pragma unroll
      for (int nt = 0; nt < 4; ++nt)
        acc[mt][nt] = __builtin_amdgcn_mfma_f32_16x16x32_bf16(
            af[mt], bfr[nt], acc[mt][nt], 0, 0, 0);
    __syncthreads();
  }

  // epilogue: C/D layout col = lane&15, row = g*4 + j
  #pragma unroll
  for (int mt = 0; mt < 3; ++mt) {
    int row = wv * 48 + mt * 16 + g * 4;
    #pragma unroll
    for (int nt = 0; nt < 4; ++nt) {
      int col = colBase + nt * 16 + ln15;
      if (col < NCOL_) {
        #pragma unroll
        for (int j = 0; j < 4; ++j)
          A[(size_t)(row + j) * NCOL_ + col] = acc[mt][nt][j];
      }
    }
  }
}

// ---------------- kernel 4a: z[blk][r][je] = dot(A-row-slice, ent) ----------
__global__ __launch_bounds__(256) void k_score_z(
    const float* __restrict__ A, const float* __restrict__ ent,
    float* __restrict__ zbuf) {
  int blk = blockIdx.x;         // b*12 + ke
  int rc = blockIdx.y;          // 0..12
  int b = blk / E_;
  int t = threadIdx.x;
  int lane = t & 63;
  int wv = t >> 6;
  __shared__ float entS[E_ * D_];   // 38784 B
  {
    const float4* src = (const float4*)(ent + (size_t)b * E_ * D_);
    float4* dst = (float4*)entS;
    for (int i = t; i < E_ * D_ / 4; i += 256) dst[i] = src[i];
  }
  __syncthreads();
  int r = rc * 4 + wv;
  if (r >= D2_) return;
  const float* arow = A + (size_t)blk * NCOL_ + (size_t)r * D_;
  float p[E_];
  #pragma unroll
  for (int je = 0; je < E_; ++je) p[je] = 0.f;
  for (int j = lane; j < D_; j += 64) {
    float a = arow[j];
    #pragma unroll
    for (int je = 0; je < E_; ++je) p[je] += a * entS[je * D_ + j];
  }
  #pragma unroll
  for (int je = 0; je < E_; ++je)
    #pragma unroll
    for (int off = 32; off > 0; off >>= 1)
      p[je] += __shfl_down(p[je], off, 64);
  if (lane == 0) {
    #pragma unroll
    for (int je = 0; je < E_; ++je)
      zbuf[(size_t)blk * (D2_ * E_) + r * E_ + je] = p[je];
  }
}

// ---------------- kernel 4b: BN + R projection ------------------------------
__global__ __launch_bounds__(256) void k_out(
    const float* __restrict__ zbuf, const float* __restrict__ Rm,
    const float* __restrict__ gam, const float* __restrict__ bet,
    const float* __restrict__ mu, const float* __restrict__ var,
    float* __restrict__ out) {
  int blk = blockIdx.x;   // b*12+ke
  int t = threadIdx.x;
  __shared__ float zS[D2_ * E_];       // 600
  __shared__ float Rs[RNUM_ * D2_];    // 4850
  for (int i = t; i < D2_ * E_; i += 256) {
    int r = i / E_;
    float z = zbuf[(size_t)blk * (D2_ * E_) + i];
    zS[i] = (z - mu[r]) * rsqrtf(var[r] + 1e-5f) * gam[r] + bet[r];
  }
  for (int i = t; i < RNUM_ * D2_; i += 256) Rs[i] = Rm[i];
  __syncthreads();
  for (int o = t; o < E_ * RNUM_; o += 256) {
    int je = o / RNUM_;
    int k = o % RNUM_;
    float s = 0.f;
    #pragma unroll
    for (int r = 0; r < D2_; ++r) s += zS[r * E_ + je] * Rs[k * D2_ + r];
    out[(size_t)blk * (E_ * RNUM_) + o] = s;
  }
}

extern "C" void kernel_launch(void* const* d_in, const int* in_sizes, int n_in,
                              void* d_out, int out_size, void* d_ws, size_t ws_size,
                              hipStream_t stream) {
  const float* enc  = (const float*)d_in[0];
  const int*  etype = (const int*)d_in[1];
  const int*  eidv  = (const int*)d_in[2];
  const int*  midv  = (const int*)d_in[3];
  const float* tbl  = (const float*)d_in[4];
  const float* temb = (const float*)d_in[5];
  const float* iemb = (const float*)d_in[6];
  const float* W    = (const float*)d_in[7];
  const float* Rm   = (const float*)d_in[8];
  const float* gam  = (const float*)d_in[9];
  const float* bet  = (const float*)d_in[10];
  const float* mu   = (const float*)d_in[11];
  const float* var  = (const float*)d_in[12];

  float* ws   = (float*)d_ws;
  float* x    = ws;                                  // 478336 floats
  float* ent  = x + (size_t)B_ * NODES_ * D_;        // +155136
  float* A    = ent + (size_t)MROWS_ * D_;           // +7756800
  float* zbuf = A + (size_t)MROWS_ * NCOL_;          // +115200
  short* eswz = (short*)(zbuf + (size_t)MROWS_ * D2_ * E_);  // 319488 B
  float* out  = (float*)d_out;

  hipLaunchKernelGGL(k_mention_pool, dim3(B_ * NODES_), dim3(256), 0, stream,
                     enc, etype, eidv, midv, temb, iemb, x);
  hipLaunchKernelGGL(k_entity_pool, dim3(MROWS_), dim3(256), 0, stream,
                     x, tbl, ent, eswz);
  hipLaunchKernelGGL(k_gemm, dim3((NCOL_ + 63) / 64), dim3(256), 0, stream,
                     W, eswz, A);
  hipLaunchKernelGGL(k_score_z, dim3(MROWS_, 13), dim3(256), 0, stream,
                     A, ent, zbuf);
  hipLaunchKernelGGL(k_out, dim3(MROWS_), dim3(256), 0, stream,
                     zbuf, Rm, gam, bet, mu, var, out);
}